// Round 1
// baseline (1531.801 us; speedup 1.0000x reference)
//
#include <hip/hip_runtime.h>
#include <math.h>

typedef float f4u __attribute__((ext_vector_type(4), aligned(4)));
typedef float nfloat4 __attribute__((ext_vector_type(4), aligned(16)));

__device__ __forceinline__ float softsign(float v) {
    float d = 1.0f + fabsf(v);
    return v * __builtin_amdgcn_rcpf(d);
}
__device__ __forceinline__ void nt_store4(float* p, float a, float b, float c, float d) {
    nfloat4 v; v.x = a; v.y = b; v.z = c; v.w = d;
    __builtin_nontemporal_store(v, (nfloat4*)p);
}
__device__ __forceinline__ int clamp63(int v) { return v < 0 ? 0 : (v > 63 ? 63 : v); }

__device__ __forceinline__ void load_row6(const float* __restrict__ row, int x0, float r[6]) {
    const float4 v = *(const float4*)(row + x0);
    r[0] = row[x0 == 0 ? 0 : x0 - 1];
    r[1] = v.x; r[2] = v.y; r[3] = v.z; r[4] = v.w;
    r[5] = row[x0 == 60 ? 63 : x0 + 4];
}

// -------- first layer: 2 input channels -> 1 channel (unchanged) --------
__global__ __launch_bounds__(256) void conv_first(const float* __restrict__ in0,
                                                  const float* __restrict__ in1,
                                                  float* __restrict__ out,
                                                  const float* __restrict__ w,
                                                  const float* __restrict__ bias) {
    int tid = blockIdx.x * 256 + threadIdx.x;
    int xq = (tid & 15) << 2;
    int y  = (tid >> 4) & 63;
    int z0 = ((tid >> 10) & 15) << 2;
    int b  = tid >> 14;
    const float* base0 = in0 + (size_t)b * 262144;
    const float* base1 = in1 + (size_t)b * 262144;

    float acc[4][4];
    #pragma unroll
    for (int i = 0; i < 4; ++i)
        #pragma unroll
        for (int j = 0; j < 4; ++j) acc[i][j] = 0.0f;

    #pragma unroll
    for (int zi = 0; zi < 6; ++zi) {
        int zin = clamp63(z0 + zi - 1);
        const float* p0 = base0 + zin * 4096;
        const float* p1 = base1 + zin * 4096;
        #pragma unroll
        for (int dy = 0; dy < 3; ++dy) {
            int yin = clamp63(y + dy - 1);
            float r0[6], r1[6];
            load_row6(p0 + yin * 64, xq, r0);
            load_row6(p1 + yin * 64, xq, r1);
            #pragma unroll
            for (int dz = 0; dz < 3; ++dz) {
                int zo = zi - dz;
                if (zo >= 0 && zo < 4) {
                    #pragma unroll
                    for (int dx = 0; dx < 3; ++dx) {
                        float w0v = w[dz * 9 + dy * 3 + dx];
                        float w1v = w[27 + dz * 9 + dy * 3 + dx];
                        #pragma unroll
                        for (int xx = 0; xx < 4; ++xx) {
                            acc[zo][xx] = fmaf(w0v, r0[xx + dx], acc[zo][xx]);
                            acc[zo][xx] = fmaf(w1v, r1[xx + dx], acc[zo][xx]);
                        }
                    }
                }
            }
        }
    }
    float bv = *bias;
    float* obase = out + (size_t)b * 262144 + (size_t)z0 * 4096 + y * 64 + xq;
    #pragma unroll
    for (int zo = 0; zo < 4; ++zo) {
        float4 o;
        o.x = softsign(acc[zo][0] + bv);
        o.y = softsign(acc[zo][1] + bv);
        o.z = softsign(acc[zo][2] + bv);
        o.w = softsign(acc[zo][3] + bv);
        *(float4*)(obase + zo * 4096) = o;
    }
}

// ---- fused PAIR of middle layers: output tile 64x * 8y * 8z per block ----
// Staged input : 12 planes (z0-2..z0+9 cl) x 12 rows (y0-2..y0+9 cl), shifted x
//                layout (pos p holds x=p-1; dups at 0,64,65). 39.2 KB.
// Intermediate : 10 planes (z0-1..z0+8 cl) x 10 rows (y0-1..y0+8 cl), unshifted
//                x layout (pos p holds x=p; dups at 64,65). 27.2 KB.
// Total LDS 66,368 B -> 2 blocks/CU. Grid 1024 = 8 xcd-z-slabs x 16 b x 8 y-tiles.
// KEY edge rule: intermediate slot (pi,r) is computed AT the clamped global
// coordinate (clamp(z0-1+pi), clamp(y0-1+r)) -- its input rows are looked up by
// clamped-global -> staged-index mapping, NOT by naive pi+dz/r+dy, which is
// wrong at volume edges (staged clamp composes differently than edge-pad).
#define LROW   68
#define SPLANE (12 * LROW)   // staged plane stride (12 rows)
#define MPLANE (10 * LROW)   // intermediate plane stride (10 rows)

__global__ __launch_bounds__(256) void conv_mid2(const float* __restrict__ in,
                                                 float* __restrict__ out,
                                                 const float* __restrict__ w1,
                                                 const float* __restrict__ w2,
                                                 const float* __restrict__ b1,
                                                 const float* __restrict__ b2) {
    __shared__ float sA[12 * SPLANE];   // 9792 floats
    __shared__ float sM[10 * MPLANE];   // 6800 floats

    int blk = blockIdx.x;
    int xcd = blk & 7;
    int jj  = blk >> 3;                 // 0..127
    int b   = jj & 15;
    int y0  = ((jj >> 4) & 7) << 3;     // 0,8,...,56
    int z0  = xcd << 3;                 // XCD-affine z-slab

    int t = threadIdx.x;
    int l = t & 15;
    int g = t >> 4;

    const float* base = in + (size_t)b * 262144;

    float wv1[27], wv2[27];
    #pragma unroll
    for (int i = 0; i < 27; ++i) { wv1[i] = w1[i]; wv2[i] = w2[i]; }
    float b1v = *b1;
    float b2v = *b2;

    // ---- stage 144 rows (12 planes x 12 rows); batched loads, shifted layout ----
    {
        int off = (l == 0) ? 0 : (4 * l - 1);
        #pragma unroll
        for (int half = 0; half < 2; ++half) {
            const int cnt = half ? 4 : 5;
            float* lrows[5]; f4u mv[5]; float tv[5];
            #pragma unroll
            for (int it = 0; it < cnt; ++it) {
                int rid = (half * 5 + it) * 16 + g;      // 0..143, all valid
                int pa = rid / 12;
                int s  = rid - pa * 12;
                const float* grow = base + clamp63(z0 - 2 + pa) * 4096 + clamp63(y0 - 2 + s) * 64;
                lrows[it] = &sA[pa * SPLANE + s * LROW];
                mv[it] = *(const f4u*)(grow + off);
                tv[it] = grow[63];
            }
            #pragma unroll
            for (int it = 0; it < cnt; ++it) {
                if (l == 0)
                    *(float4*)lrows[it] = (float4){mv[it].x, mv[it].x, mv[it].y, mv[it].z};
                else
                    *(float4*)(lrows[it] + 4 * l) = (float4){mv[it].x, mv[it].y, mv[it].z, mv[it].w};
                if (l == 15)
                    *(float2*)(lrows[it] + 64) = (float2){tv[it], tv[it]};
            }
        }
    }
    __syncthreads();

    // ---- phase B: layer 1 -> intermediate (10p x 10r x 16 quads = 1600 quads) ----
    #pragma unroll
    for (int itb = 0; itb < 7; ++itb) {
        int idx = itb * 256 + t;
        if (idx < 1600) {
            int pi  = idx / 160;            // 0..9
            int rem = idx - pi * 160;
            int r   = rem >> 4;             // 0..9
            int l2  = rem & 15;
            int xq2 = l2 << 2;
            int zi_g = clamp63(z0 - 1 + pi);    // global z of this intermediate plane
            int yi_g = clamp63(y0 - 1 + r);     // global y of this intermediate row
            int pas[3], ss[3];
            pas[0] = clamp63(zi_g - 1) - z0 + 2;
            pas[1] = zi_g              - z0 + 2;
            pas[2] = clamp63(zi_g + 1) - z0 + 2;
            ss[0]  = clamp63(yi_g - 1) - y0 + 2;
            ss[1]  = yi_g              - y0 + 2;
            ss[2]  = clamp63(yi_g + 1) - y0 + 2;
            float a0 = 0.f, a1 = 0.f, a2 = 0.f, a3 = 0.f;
            #pragma unroll
            for (int dz = 0; dz < 3; ++dz) {
                const float* pl = &sA[pas[dz] * SPLANE];
                #pragma unroll
                for (int dy = 0; dy < 3; ++dy) {
                    const float* lrow = pl + ss[dy] * LROW + xq2;
                    const float4 v  = *(const float4*)lrow;
                    const float2 v2 = *(const float2*)(lrow + 4);
                    float rr[6] = {v.x, v.y, v.z, v.w, v2.x, v2.y};
                    #pragma unroll
                    for (int dx = 0; dx < 3; ++dx) {
                        float ww = wv1[dz * 9 + dy * 3 + dx];
                        a0 = fmaf(ww, rr[dx + 0], a0);
                        a1 = fmaf(ww, rr[dx + 1], a1);
                        a2 = fmaf(ww, rr[dx + 2], a2);
                        a3 = fmaf(ww, rr[dx + 3], a3);
                    }
                }
            }
            float o0 = softsign(a0 + b1v), o1 = softsign(a1 + b1v);
            float o2 = softsign(a2 + b1v), o3 = softsign(a3 + b1v);
            float* orow = &sM[pi * MPLANE + r * LROW];
            *(float4*)(orow + xq2) = (float4){o0, o1, o2, o3};
            if (l2 == 15) { orow[64] = o3; orow[65] = o3; }
        }
    }
    __syncthreads();

    // ---- phase C: layer 2 -> global. thread = (xq, y_loc, z-half); 4x*1y*4z ----
    {
        int y_loc = g & 7;
        int zh    = (g >> 3) << 2;      // 0 or 4
        int xq    = l << 2;
        float acc[4][4];
        #pragma unroll
        for (int i = 0; i < 4; ++i)
            #pragma unroll
            for (int k = 0; k < 4; ++k) acc[i][k] = 0.0f;

        #pragma unroll
        for (int pp = 0; pp < 6; ++pp) {
            const float* pl = &sM[(zh + pp) * MPLANE];
            #pragma unroll
            for (int dy = 0; dy < 3; ++dy) {
                const float* row = pl + (y_loc + dy) * LROW;
                float front = row[l == 0 ? 0 : xq - 1];
                const float4 v  = *(const float4*)(row + xq);
                const float2 v2 = *(const float2*)(row + xq + 4);
                float rr[6] = {front, v.x, v.y, v.z, v.w, v2.x};
                #pragma unroll
                for (int dz = 0; dz < 3; ++dz) {
                    int zz = pp - dz;
                    if (zz >= 0 && zz < 4) {
                        #pragma unroll
                        for (int dx = 0; dx < 3; ++dx) {
                            float ww = wv2[dz * 9 + dy * 3 + dx];
                            #pragma unroll
                            for (int xx = 0; xx < 4; ++xx)
                                acc[zz][xx] = fmaf(ww, rr[xx + dx], acc[zz][xx]);
                        }
                    }
                }
            }
        }
        int y = y0 + y_loc;
        float* obase = out + (size_t)b * 262144 + (size_t)(z0 + zh) * 4096 + y * 64 + xq;
        #pragma unroll
        for (int zz = 0; zz < 4; ++zz) {
            float4 o;
            o.x = softsign(acc[zz][0] + b2v);
            o.y = softsign(acc[zz][1] + b2v);
            o.z = softsign(acc[zz][2] + b2v);
            o.w = softsign(acc[zz][3] + b2v);
            *(float4*)(obase + zz * 4096) = o;   // normal store: stays cached
        }
    }
}

// -------- last layer: 1 -> 3 channels + strided downsample outputs (unchanged) --------
__global__ __launch_bounds__(256) void conv_last(const float* __restrict__ in,
                                                 float* __restrict__ out,
                                                 const float* __restrict__ w,
                                                 const float* __restrict__ bias) {
    int tid = blockIdx.x * 256 + threadIdx.x;
    int xq = (tid & 15) << 2;
    int y  = (tid >> 4) & 63;
    int z0 = ((tid >> 10) & 15) << 2;
    int b  = tid >> 14;
    const float* base = in + (size_t)b * 262144;

    float acc[4][3][4];
    #pragma unroll
    for (int i = 0; i < 4; ++i)
        #pragma unroll
        for (int c = 0; c < 3; ++c)
            #pragma unroll
            for (int j = 0; j < 4; ++j) acc[i][c][j] = 0.0f;

    #pragma unroll
    for (int zi = 0; zi < 6; ++zi) {
        int zin = clamp63(z0 + zi - 1);
        const float* plane = base + zin * 4096;
        #pragma unroll
        for (int dy = 0; dy < 3; ++dy) {
            int yin = clamp63(y + dy - 1);
            float r[6];
            load_row6(plane + yin * 64, xq, r);
            #pragma unroll
            for (int dz = 0; dz < 3; ++dz) {
                int zo = zi - dz;
                if (zo >= 0 && zo < 4) {
                    #pragma unroll
                    for (int c = 0; c < 3; ++c) {
                        #pragma unroll
                        for (int dx = 0; dx < 3; ++dx) {
                            float wc = w[c * 27 + dz * 9 + dy * 3 + dx];
                            #pragma unroll
                            for (int xx = 0; xx < 4; ++xx)
                                acc[zo][c][xx] = fmaf(wc, r[xx + dx], acc[zo][c][xx]);
                        }
                    }
                }
            }
        }
    }

    float* r64 = out;
    float* r32 = out + 12582912;
    float* r16 = r32 + 1572864;
    float* r8  = r16 + 196608;

    float vals[4][3][4];
    #pragma unroll
    for (int zo = 0; zo < 4; ++zo)
        #pragma unroll
        for (int c = 0; c < 3; ++c) {
            float bv = bias[c];
            #pragma unroll
            for (int xx = 0; xx < 4; ++xx)
                vals[zo][c][xx] = softsign(acc[zo][c][xx] + bv);
        }

    #pragma unroll
    for (int c = 0; c < 3; ++c) {
        float* cb = r64 + ((size_t)b * 3 + c) * 262144 + (size_t)z0 * 4096 + y * 64 + xq;
        #pragma unroll
        for (int zo = 0; zo < 4; ++zo) {
            nt_store4(cb + zo * 4096,
                      vals[zo][c][0], vals[zo][c][1], vals[zo][c][2], vals[zo][c][3]);
        }
    }
    if ((y & 1) == 0) {
        #pragma unroll
        for (int c = 0; c < 3; ++c) {
            size_t cb = ((size_t)b * 3 + c) * 32768 + (size_t)(y >> 1) * 32;
            #pragma unroll
            for (int zo = 0; zo < 4; zo += 2) {
                size_t zb = cb + (size_t)((z0 + zo) >> 1) * 1024;
                __builtin_nontemporal_store(vals[zo][c][0], r32 + zb + ((xq + 0) >> 1));
                __builtin_nontemporal_store(vals[zo][c][2], r32 + zb + ((xq + 2) >> 1));
            }
        }
    }
    if ((y & 3) == 0) {
        #pragma unroll
        for (int c = 0; c < 3; ++c) {
            __builtin_nontemporal_store(vals[0][c][0],
                r16 + ((size_t)b * 3 + c) * 4096 + (size_t)(z0 >> 2) * 256 + (y >> 2) * 16 + (xq >> 2));
        }
    }
    if ((y & 7) == 0 && (z0 & 7) == 0 && (xq & 7) == 0) {
        #pragma unroll
        for (int c = 0; c < 3; ++c) {
            __builtin_nontemporal_store(vals[0][c][0],
                r8 + ((size_t)b * 3 + c) * 512 + (size_t)(z0 >> 3) * 64 + (y >> 3) * 8 + (xq >> 3));
        }
    }
}

extern "C" void kernel_launch(void* const* d_in, const int* in_sizes, int n_in,
                              void* d_out, int out_size, void* d_ws, size_t ws_size,
                              hipStream_t stream) {
    const float* preop = (const float*)d_in[0];
    const float* intra = (const float*)d_in[1];
    const float* w0    = (const float*)d_in[2];
    const float* b0p   = (const float*)d_in[3];
    const float* wsp   = (const float*)d_in[4];
    const float* bsp   = (const float*)d_in[5];
    const float* wX    = (const float*)d_in[6];
    const float* bX    = (const float*)d_in[7];
    float* out = (float*)d_out;

    float* buf0 = (float*)d_ws;
    float* buf1 = out;   // ping-pong scratch inside the (larger) output buffer

    conv_first<<<dim3(1024), dim3(256), 0, stream>>>(preop, intra, buf0, w0, b0p);
    // 100 mids = 50 fused pairs. k even: buf0->buf1, k odd: buf1->buf0; k=49 -> buf0.
    for (int k = 0; k < 50; ++k) {
        const float* src = (k & 1) ? buf1 : buf0;
        float* dst       = (k & 1) ? buf0 : buf1;
        conv_mid2<<<dim3(1024), dim3(256), 0, stream>>>(src, dst,
                                                        wsp + (2 * k) * 27,
                                                        wsp + (2 * k + 1) * 27,
                                                        bsp + 2 * k,
                                                        bsp + 2 * k + 1);
    }
    conv_last<<<dim3(1024), dim3(256), 0, stream>>>(buf0, out, wX, bX);
}